// Round 1
// baseline (286.976 us; speedup 1.0000x reference)
//
#include <hip/hip_runtime.h>
#include <math.h>

// Problem constants
constexpr int B_ = 4, C_ = 256, H4 = 96, W4 = 320, HF = 384, WF = 1280;
constexpr int CHUNKS = 5;              // 320 / 64 px per block
constexpr float EPSV = 1e-6f;
constexpr int LOW = B_ * H4 * W4;      // 122880
constexpr int FULL = B_ * HF * WF;     // 1966080

// Per-iteration accumulation: lane owns pixel quad [xo..xo+3] of one channel.
// wv[0..11] = fR pixels xo-4 .. xo+7 (left/own/right float4 blocks).
// dot[k][p] += fL[xo+p] * fR[xo+p+(k-3)]  ->  wv index p+k+1 in [1,10].
__device__ __forceinline__ void accum_batch(
    const float4 vL, const float4 wA, const float4 wB, const float4 wC,
    const bool rsel, float* __restrict__ acc, float* __restrict__ sL,
    float* __restrict__ sR, float* __restrict__ sH)
{
    const float lv[4]  = {vL.x, vL.y, vL.z, vL.w};
    const float wv[12] = {wA.x, wA.y, wA.z, wA.w,
                          wB.x, wB.y, wB.z, wB.w,
                          wC.x, wC.y, wC.z, wC.w};
#pragma unroll
    for (int k = 0; k < 7; ++k)
#pragma unroll
        for (int p = 0; p < 4; ++p)
            acc[k * 4 + p] = fmaf(lv[p], wv[p + k + 1], acc[k * 4 + p]);
#pragma unroll
    for (int p = 0; p < 4; ++p) {
        sL[p] = fmaf(lv[p], lv[p], sL[p]);
        sR[p] = fmaf(wv[4 + p], wv[4 + p], sR[p]);
    }
    // Halo norms: q==0 lanes accumulate left-halo pixels (wv[1..3] = xo-3..xo-1),
    // q==15 lanes the right-halo pixels (wv[8..10] = xo+4..xo+6). Garbage on
    // other lanes, never read.
#pragma unroll
    for (int j = 0; j < 3; ++j) {
        const float t = rsel ? wv[8 + j] : wv[1 + j];
        sH[j] = fmaf(t, t, sH[j]);
    }
}

// Phase 1: banded cosine correlation + softmax + downsampled disp -> dref, conf.
// 256 threads = 4 waves; wave w reduces channels [64w, 64w+64).
// Lane = (csub, q): channel sub-slot csub = lane>>4, pixel quad q = lane&15.
// Hot loop is pure {4x global_load_dwordx4 + FMA}: the 7-neighborhood of fR
// comes from the lane's own overlapping left/own/right quad loads (L1 absorbs
// the 3x refetch; same cache lines). No LDS, no barriers, no lgkmcnt in the
// channel loop -> loads stay deeply in flight (vmcnt-counted waits only).
__global__ __launch_bounds__(256)
void phase1(const float* __restrict__ fL, const float* __restrict__ fR,
            const float* __restrict__ D, float* __restrict__ dref,
            float* __restrict__ conf)
{
    const int bi = blockIdx.x;
    const int chunk = bi % CHUNKS;
    const int y = (bi / CHUNKS) % H4;
    const int b = bi / (CHUNKS * H4);
    const int tid = threadIdx.x;
    const int wave = tid >> 6;
    const int lane = tid & 63;
    const int q = lane & 15;
    const int csub = lane >> 4;
    const int x0 = chunk * 64;
    const int xo = x0 + 4 * q;

    const size_t chanStride = (size_t)H4 * W4;                 // 30720
    const size_t rowBase = (((size_t)b * C_) * H4 + y) * W4;

    // Neighbor quad starts; circular wrap (jnp.roll) only at row ends.
    int lx = xo - 4; if (lx < 0)   lx += W4;   // wraps only for chunk 0, q 0
    int rx = xo + 4; if (rx >= W4) rx -= W4;   // wraps only for chunk 4, q 15

    const int c0 = wave * 64 + csub;
    const float* pL = fL + rowBase + (size_t)c0 * chanStride;
    const float* pR = fR + rowBase + (size_t)c0 * chanStride;
    const size_t step = 4 * chanStride;        // 4 channels per iteration

    float acc[28];
#pragma unroll
    for (int i = 0; i < 28; ++i) acc[i] = 0.f;
    float sL[4] = {0.f, 0.f, 0.f, 0.f};
    float sR[4] = {0.f, 0.f, 0.f, 0.f};
    float sH[3] = {0.f, 0.f, 0.f};
    const bool rsel = (q == 15);

    // Prologue: channel c0
    float4 vL = *(const float4*)(pL + xo);
    float4 wA = *(const float4*)(pR + lx);
    float4 wB = *(const float4*)(pR + xo);
    float4 wC = *(const float4*)(pR + rx);

    size_t off = 0;
    for (int it = 0; it < 16; ++it) {          // 16 iters x 4 csub = 64 channels/wave
        const float4 cL = vL, cA = wA, cB = wB, cC = wC;
        if (it < 15) {                          // issue next channel's loads first
            off += step;
            vL = *(const float4*)(pL + off + xo);
            wA = *(const float4*)(pR + off + lx);
            wB = *(const float4*)(pR + off + xo);
            wC = *(const float4*)(pR + off + rx);
        }
        accum_batch(cL, cA, cB, cC, rsel, acc, sL, sR, sH);
    }

    // Reduce across the four csub groups (lane-id bits 4 and 5).
#pragma unroll
    for (int i = 0; i < 28; ++i) {
        acc[i] += __shfl_xor(acc[i], 16);
        acc[i] += __shfl_xor(acc[i], 32);
    }
#pragma unroll
    for (int p = 0; p < 4; ++p) {
        sL[p] += __shfl_xor(sL[p], 16); sL[p] += __shfl_xor(sL[p], 32);
        sR[p] += __shfl_xor(sR[p], 16); sR[p] += __shfl_xor(sR[p], 32);
    }
#pragma unroll
    for (int j = 0; j < 3; ++j) {
        sH[j] += __shfl_xor(sH[j], 16);
        sH[j] += __shfl_xor(sH[j], 32);
    }

    // Cross-wave reduction (one-time epilogue).
    __shared__ float rec[4][16][37];   // [wave][quad][28 dot + 4 sL + 4 sR], pad
    __shared__ float hrec[4][2][3];    // [wave][left/right][3 halo norms]
    __shared__ float sss[70];          // squared norms for pixels x0-3 .. x0+66
    if (lane < 16) {
#pragma unroll
        for (int i = 0; i < 28; ++i) rec[wave][lane][i] = acc[i];
#pragma unroll
        for (int p = 0; p < 4; ++p) {
            rec[wave][lane][28 + p] = sL[p];
            rec[wave][lane][32 + p] = sR[p];
        }
    }
    if (lane == 0) {
#pragma unroll
        for (int j = 0; j < 3; ++j) hrec[wave][0][j] = sH[j];
    }
    if (lane == 15) {
#pragma unroll
        for (int j = 0; j < 3; ++j) hrec[wave][1][j] = sH[j];
    }
    __syncthreads();

    float D7[7];
    float rsL = 0.f;
    if (tid < 64) {
        const int qq = tid >> 2, pp = tid & 3;
#pragma unroll
        for (int k = 0; k < 7; ++k)
            D7[k] = rec[0][qq][4 * k + pp] + rec[1][qq][4 * k + pp]
                  + rec[2][qq][4 * k + pp] + rec[3][qq][4 * k + pp];
        rsL = rec[0][qq][28 + pp] + rec[1][qq][28 + pp]
            + rec[2][qq][28 + pp] + rec[3][qq][28 + pp];
        const float rsR = rec[0][qq][32 + pp] + rec[1][qq][32 + pp]
                        + rec[2][qq][32 + pp] + rec[3][qq][32 + pp];
        sss[3 + tid] = rsR;
        if (tid < 3)
            sss[tid] = hrec[0][0][tid] + hrec[1][0][tid]
                     + hrec[2][0][tid] + hrec[3][0][tid];
        if (tid >= 61) {
            const int j = tid - 61;   // pixels x0+64..x0+66 -> sss[67..69]
            sss[67 + j] = hrec[0][1][j] + hrec[1][1][j]
                        + hrec[2][1][j] + hrec[3][1][j];
        }
    }
    __syncthreads();

    if (tid < 64) {
        const float nLv = fmaxf(sqrtf(rsL), EPSV);
        float cost[7];
#pragma unroll
        for (int k = 0; k < 7; ++k) {
            // k indexes neighbor x+(k-3); reference cost[i] (d=i-3) uses x+(3-i)
            const float nR = fmaxf(sqrtf(sss[tid + k]), EPSV);
            cost[6 - k] = (D7[k] / (nLv * nR)) * 10.0f;   // /TEMP, TEMP=0.1
        }
        float m = cost[0];
#pragma unroll
        for (int i = 1; i < 7; ++i) m = fmaxf(m, cost[i]);
        float sum = 0.f, dsum = 0.f;
#pragma unroll
        for (int i = 0; i < 7; ++i) {
            const float e = __expf(cost[i] - m);
            sum += e;
            dsum += e * (float)(i - 3);
        }
        const float delta = dsum / sum;
        const float cf = 1.0f / sum;               // max p = exp(0)/sum

        // Exact 4x downsample of disp_full: y0=4y+1,y1=4y+2, wy=wx=0.5 -> mean of 2x2, /4
        const int xpix = x0 + tid;
        const int Y0 = 4 * y + 1, X0 = 4 * xpix + 1;
        const size_t dbase = ((size_t)b * HF + Y0) * WF + X0;
        const float s4 = D[dbase] + D[dbase + 1] + D[dbase + WF] + D[dbase + WF + 1];
        const float disp0 = s4 * 0.0625f;          // (sum/4)/4

        const size_t o = ((size_t)b * H4 + y) * W4 + xpix;
        dref[o] = disp0 + delta;
        conf[o] = cf;
    }
}

// dq = dref - 0.2 * Laplacian(dref) computed on the fly (zero padding)
__device__ __forceinline__ float dq_val(const float* __restrict__ dref,
                                        size_t base, int yq, int xq)
{
    size_t i = base + (size_t)yq * W4 + xq;
    float c  = dref[i];
    float up = (yq > 0)      ? dref[i - W4] : 0.f;
    float dn = (yq < H4 - 1) ? dref[i + W4] : 0.f;
    float lf = (xq > 0)      ? dref[i - 1]  : 0.f;
    float rt = (xq < W4 - 1) ? dref[i + 1]  : 0.f;
    return c - 0.2f * (up + dn + lf + rt - 4.f * c);
}

// Phase 2 (fused): 4x bilinear upsample of dq (*4) and conf
__global__ void phase2(const float* __restrict__ dref, const float* __restrict__ cf,
                       float* __restrict__ out)
{
    int i = blockIdx.x * blockDim.x + threadIdx.x;
    if (i >= FULL) return;
    int X = i % WF;
    int Y = (i / WF) % HF;
    int b = i / (WF * HF);
    float ys = fmaxf((Y + 0.5f) * 0.25f - 0.5f, 0.f);
    float xs = fmaxf((X + 0.5f) * 0.25f - 0.5f, 0.f);
    float y0f = floorf(ys), x0f = floorf(xs);
    float wy = ys - y0f, wx = xs - x0f;
    int y0 = min((int)y0f, H4 - 1);
    int x0 = min((int)x0f, W4 - 1);
    int y1 = min(y0 + 1, H4 - 1);
    int x1 = min(x0 + 1, W4 - 1);
    size_t base = (size_t)b * (H4 * W4);

    float d = (1.f - wy) * ((1.f - wx) * dq_val(dref, base, y0, x0) + wx * dq_val(dref, base, y0, x1))
            +        wy  * ((1.f - wx) * dq_val(dref, base, y1, x0) + wx * dq_val(dref, base, y1, x1));

    size_t i00 = base + (size_t)y0 * W4 + x0;
    size_t i01 = base + (size_t)y0 * W4 + x1;
    size_t i10 = base + (size_t)y1 * W4 + x0;
    size_t i11 = base + (size_t)y1 * W4 + x1;
    float cv = (1.f - wy) * ((1.f - wx) * cf[i00] + wx * cf[i01])
             +        wy  * ((1.f - wx) * cf[i10] + wx * cf[i11]);

    out[i] = 4.0f * d;
    out[(size_t)FULL + i] = cv;
}

extern "C" void kernel_launch(void* const* d_in, const int* in_sizes, int n_in,
                              void* d_out, int out_size, void* d_ws, size_t ws_size,
                              hipStream_t stream)
{
    const float* fL = (const float*)d_in[0];
    const float* fR = (const float*)d_in[1];
    const float* D  = (const float*)d_in[2];
    float* out  = (float*)d_out;
    float* ws   = (float*)d_ws;
    float* dref = ws;
    float* conf = ws + LOW;

    phase1<<<B_ * H4 * CHUNKS, 256, 0, stream>>>(fL, fR, D, dref, conf);
    phase2<<<(FULL + 255) / 256, 256, 0, stream>>>(dref, conf, out);
}

// Round 2
// 282.587 us; speedup vs baseline: 1.0155x; 1.0155x over previous
//
#include <hip/hip_runtime.h>
#include <math.h>

// Problem constants
constexpr int B_ = 4, C_ = 256, H4 = 96, W4 = 320, HF = 384, WF = 1280;
constexpr int CHUNKS = 5;              // 320 / 64 px per block
constexpr float EPSV = 1e-6f;
constexpr int LOW = B_ * H4 * W4;      // 122880
constexpr int FULL = B_ * HF * WF;     // 1966080

// Per-iteration accumulation: lane owns pixel quad [xo..xo+3] of one channel.
// wv[0..11] = fR pixels xo-4 .. xo+7 (left/own/right float4 blocks).
// dot[k][p] += fL[xo+p] * fR[xo+p+(k-3)]  ->  wv index p+k+1 in [1,10].
__device__ __forceinline__ void accum_batch(
    const float4 vL, const float4 wA, const float4 wB, const float4 wC,
    const bool rsel, float* __restrict__ acc, float* __restrict__ sL,
    float* __restrict__ sR, float* __restrict__ sH)
{
    const float lv[4]  = {vL.x, vL.y, vL.z, vL.w};
    const float wv[12] = {wA.x, wA.y, wA.z, wA.w,
                          wB.x, wB.y, wB.z, wB.w,
                          wC.x, wC.y, wC.z, wC.w};
#pragma unroll
    for (int k = 0; k < 7; ++k)
#pragma unroll
        for (int p = 0; p < 4; ++p)
            acc[k * 4 + p] = fmaf(lv[p], wv[p + k + 1], acc[k * 4 + p]);
#pragma unroll
    for (int p = 0; p < 4; ++p) {
        sL[p] = fmaf(lv[p], lv[p], sL[p]);
        sR[p] = fmaf(wv[4 + p], wv[4 + p], sR[p]);
    }
    // Halo norms: q==0 lanes accumulate left-halo pixels (wv[1..3]),
    // q==15 lanes the right-halo pixels (wv[8..10]). Garbage elsewhere, never read.
#pragma unroll
    for (int j = 0; j < 3; ++j) {
        const float t = rsel ? wv[8 + j] : wv[1 + j];
        sH[j] = fmaf(t, t, sH[j]);
    }
}

// Phase 1: banded cosine correlation + softmax + downsampled disp -> dref, conf.
// 256 threads = 4 waves; wave w reduces channels [64w, 64w+64).
// Lane = (csub, q): channel sub-slot csub = lane>>4, pixel quad q = lane&15.
//
// Round-2 structure: the 16-iteration channel loop is FULLY UNROLLED with an
// explicit 3-deep rotating register buffer (issue generation g+2, consume g).
// asm memory fences pin each generation's issue point so the compiler cannot
// sink loads next to their use (round-1 failure mode: VGPR=56, loads consumed
// one branch after issue -> vmcnt(0) convoy, 1.77 TB/s). Memory clobbers do
// not force waitcnt on in-flight loads; first consume of gen g waits with 8
// newer wave-loads still in flight (~12 KB/wave MLP).
__global__ __launch_bounds__(256)
void phase1(const float* __restrict__ fL, const float* __restrict__ fR,
            const float* __restrict__ D, float* __restrict__ dref,
            float* __restrict__ conf)
{
    const int bi = blockIdx.x;
    const int chunk = bi % CHUNKS;
    const int y = (bi / CHUNKS) % H4;
    const int b = bi / (CHUNKS * H4);
    const int tid = threadIdx.x;
    const int wave = tid >> 6;
    const int lane = tid & 63;
    const int q = lane & 15;
    const int csub = lane >> 4;
    const int x0 = chunk * 64;
    const int xo = x0 + 4 * q;

    const size_t chanStride = (size_t)H4 * W4;                 // 30720
    const size_t rowBase = (((size_t)b * C_) * H4 + y) * W4;

    // Neighbor quad starts; circular wrap (jnp.roll) only at row ends.
    int lx = xo - 4; if (lx < 0)   lx += W4;   // wraps only for chunk 0, q 0
    int rx = xo + 4; if (rx >= W4) rx -= W4;   // wraps only for chunk 4, q 15

    const int c0 = wave * 64 + csub;
    const float* pL = fL + rowBase + (size_t)c0 * chanStride;
    const float* pR = fR + rowBase + (size_t)c0 * chanStride;
    const size_t step = 4 * chanStride;        // 4 channels per iteration

    float acc[28];
#pragma unroll
    for (int i = 0; i < 28; ++i) acc[i] = 0.f;
    float sL[4] = {0.f, 0.f, 0.f, 0.f};
    float sR[4] = {0.f, 0.f, 0.f, 0.f};
    float sH[3] = {0.f, 0.f, 0.f};
    const bool rsel = (q == 15);

    // 3-deep rotating register buffers.
    float4 bL[3], bA[3], bB[3], bC[3];

    // Prologue: issue generations 0 and 1.
#pragma unroll
    for (int g = 0; g < 2; ++g) {
        const size_t o = (size_t)g * step;
        bL[g] = *(const float4*)(pL + o + xo);
        bA[g] = *(const float4*)(pR + o + lx);
        bB[g] = *(const float4*)(pR + o + xo);
        bC[g] = *(const float4*)(pR + o + rx);
    }
    asm volatile("" ::: "memory");

#pragma unroll
    for (int it = 0; it < 16; ++it) {          // 16 iters x 4 csub = 64 channels/wave
        const int cur = it % 3;
        if (it + 2 < 16) {                     // issue generation it+2
            const int nxt = (it + 2) % 3;
            const size_t o = (size_t)(it + 2) * step;
            bL[nxt] = *(const float4*)(pL + o + xo);
            bA[nxt] = *(const float4*)(pR + o + lx);
            bB[nxt] = *(const float4*)(pR + o + xo);
            bC[nxt] = *(const float4*)(pR + o + rx);
        }
        asm volatile("" ::: "memory");         // pin issue point; loads can't sink past
        accum_batch(bL[cur], bA[cur], bB[cur], bC[cur], rsel, acc, sL, sR, sH);
    }

    // Reduce across the four csub groups (lane-id bits 4 and 5).
#pragma unroll
    for (int i = 0; i < 28; ++i) {
        acc[i] += __shfl_xor(acc[i], 16);
        acc[i] += __shfl_xor(acc[i], 32);
    }
#pragma unroll
    for (int p = 0; p < 4; ++p) {
        sL[p] += __shfl_xor(sL[p], 16); sL[p] += __shfl_xor(sL[p], 32);
        sR[p] += __shfl_xor(sR[p], 16); sR[p] += __shfl_xor(sR[p], 32);
    }
#pragma unroll
    for (int j = 0; j < 3; ++j) {
        sH[j] += __shfl_xor(sH[j], 16);
        sH[j] += __shfl_xor(sH[j], 32);
    }

    // Cross-wave reduction (one-time epilogue).
    __shared__ float rec[4][16][37];   // [wave][quad][28 dot + 4 sL + 4 sR], pad
    __shared__ float hrec[4][2][3];    // [wave][left/right][3 halo norms]
    __shared__ float sss[70];          // squared norms for pixels x0-3 .. x0+66
    if (lane < 16) {
#pragma unroll
        for (int i = 0; i < 28; ++i) rec[wave][lane][i] = acc[i];
#pragma unroll
        for (int p = 0; p < 4; ++p) {
            rec[wave][lane][28 + p] = sL[p];
            rec[wave][lane][32 + p] = sR[p];
        }
    }
    if (lane == 0) {
#pragma unroll
        for (int j = 0; j < 3; ++j) hrec[wave][0][j] = sH[j];
    }
    if (lane == 15) {
#pragma unroll
        for (int j = 0; j < 3; ++j) hrec[wave][1][j] = sH[j];
    }
    __syncthreads();

    float D7[7];
    float rsL = 0.f;
    if (tid < 64) {
        const int qq = tid >> 2, pp = tid & 3;
#pragma unroll
        for (int k = 0; k < 7; ++k)
            D7[k] = rec[0][qq][4 * k + pp] + rec[1][qq][4 * k + pp]
                  + rec[2][qq][4 * k + pp] + rec[3][qq][4 * k + pp];
        rsL = rec[0][qq][28 + pp] + rec[1][qq][28 + pp]
            + rec[2][qq][28 + pp] + rec[3][qq][28 + pp];
        const float rsR = rec[0][qq][32 + pp] + rec[1][qq][32 + pp]
                        + rec[2][qq][32 + pp] + rec[3][qq][32 + pp];
        sss[3 + tid] = rsR;
        if (tid < 3)
            sss[tid] = hrec[0][0][tid] + hrec[1][0][tid]
                     + hrec[2][0][tid] + hrec[3][0][tid];
        if (tid >= 61) {
            const int j = tid - 61;   // pixels x0+64..x0+66 -> sss[67..69]
            sss[67 + j] = hrec[0][1][j] + hrec[1][1][j]
                        + hrec[2][1][j] + hrec[3][1][j];
        }
    }
    __syncthreads();

    if (tid < 64) {
        const float nLv = fmaxf(sqrtf(rsL), EPSV);
        float cost[7];
#pragma unroll
        for (int k = 0; k < 7; ++k) {
            // k indexes neighbor x+(k-3); reference cost[i] (d=i-3) uses x+(3-i)
            const float nR = fmaxf(sqrtf(sss[tid + k]), EPSV);
            cost[6 - k] = (D7[k] / (nLv * nR)) * 10.0f;   // /TEMP, TEMP=0.1
        }
        float m = cost[0];
#pragma unroll
        for (int i = 1; i < 7; ++i) m = fmaxf(m, cost[i]);
        float sum = 0.f, dsum = 0.f;
#pragma unroll
        for (int i = 0; i < 7; ++i) {
            const float e = __expf(cost[i] - m);
            sum += e;
            dsum += e * (float)(i - 3);
        }
        const float delta = dsum / sum;
        const float cf = 1.0f / sum;               // max p = exp(0)/sum

        // Exact 4x downsample of disp_full: y0=4y+1,y1=4y+2, wy=wx=0.5 -> mean of 2x2, /4
        const int xpix = x0 + tid;
        const int Y0 = 4 * y + 1, X0 = 4 * xpix + 1;
        const size_t dbase = ((size_t)b * HF + Y0) * WF + X0;
        const float s4 = D[dbase] + D[dbase + 1] + D[dbase + WF] + D[dbase + WF + 1];
        const float disp0 = s4 * 0.0625f;          // (sum/4)/4

        const size_t o = ((size_t)b * H4 + y) * W4 + xpix;
        dref[o] = disp0 + delta;
        conf[o] = cf;
    }
}

// dq = dref - 0.2 * Laplacian(dref) computed on the fly (zero padding)
__device__ __forceinline__ float dq_val(const float* __restrict__ dref,
                                        size_t base, int yq, int xq)
{
    size_t i = base + (size_t)yq * W4 + xq;
    float c  = dref[i];
    float up = (yq > 0)      ? dref[i - W4] : 0.f;
    float dn = (yq < H4 - 1) ? dref[i + W4] : 0.f;
    float lf = (xq > 0)      ? dref[i - 1]  : 0.f;
    float rt = (xq < W4 - 1) ? dref[i + 1]  : 0.f;
    return c - 0.2f * (up + dn + lf + rt - 4.f * c);
}

// Phase 2: 4x bilinear upsample of dq (*4) and conf.
// Each thread produces 4 consecutive X outputs. The x4 upsample has period-4
// weights: outputs 4k+r (r=0..3) use wx in {0.625,0.875 | x0=k-1} and
// {0.125,0.375 | x0=k}, so 4 outputs share one (y0,y1) row pair and only 3 dq
// columns {k-1,k,k+1}: 6 dq_vals + 6 conf loads replace 4x(4+4), float4 stores.
__global__ void phase2(const float* __restrict__ dref, const float* __restrict__ cf,
                       float* __restrict__ out)
{
    const int idx = blockIdx.x * blockDim.x + threadIdx.x;
    constexpr int WQ = WF / 4;                 // 320 quads per row
    if (idx >= FULL / 4) return;
    const int k = idx % WQ;
    const int Y = (idx / WQ) % HF;
    const int b = idx / (WQ * HF);

    const float ys = fmaxf((Y + 0.5f) * 0.25f - 0.5f, 0.f);
    const float y0f = floorf(ys);
    const float wy = ys - y0f;
    const int y0 = min((int)y0f, H4 - 1);
    const int y1 = min(y0 + 1, H4 - 1);
    const size_t base = (size_t)b * (H4 * W4);

    const int xa = max(k - 1, 0);
    const int xb = k;                          // k <= 319 = W4-1
    const int xc = min(k + 1, W4 - 1);

    // dq at the 3 columns x 2 rows, then y-lerp once per column.
    const float da = (1.f - wy) * dq_val(dref, base, y0, xa) + wy * dq_val(dref, base, y1, xa);
    const float db = (1.f - wy) * dq_val(dref, base, y0, xb) + wy * dq_val(dref, base, y1, xb);
    const float dc = (1.f - wy) * dq_val(dref, base, y0, xc) + wy * dq_val(dref, base, y1, xc);

    const size_t r0 = base + (size_t)y0 * W4;
    const size_t r1 = base + (size_t)y1 * W4;
    const float ca = (1.f - wy) * cf[r0 + xa] + wy * cf[r1 + xa];
    const float cb = (1.f - wy) * cf[r0 + xb] + wy * cf[r1 + xb];
    const float cc = (1.f - wy) * cf[r0 + xc] + wy * cf[r1 + xc];

    // r=0: x0=k-1 wx=0.625; r=1: x0=k-1 wx=0.875; r=2: x0=k wx=0.125; r=3: x0=k wx=0.375
    float4 dv, cv;
    dv.x = 4.0f * (0.375f * da + 0.625f * db);
    dv.y = 4.0f * (0.125f * da + 0.875f * db);
    dv.z = 4.0f * (0.875f * db + 0.125f * dc);
    dv.w = 4.0f * (0.625f * db + 0.375f * dc);
    cv.x = 0.375f * ca + 0.625f * cb;
    cv.y = 0.125f * ca + 0.875f * cb;
    cv.z = 0.875f * cb + 0.125f * cc;
    cv.w = 0.625f * cb + 0.375f * cc;

    const size_t o = (((size_t)b * HF + Y) * WF) + 4 * k;
    *(float4*)&out[o] = dv;
    *(float4*)&out[(size_t)FULL + o] = cv;
}

extern "C" void kernel_launch(void* const* d_in, const int* in_sizes, int n_in,
                              void* d_out, int out_size, void* d_ws, size_t ws_size,
                              hipStream_t stream)
{
    const float* fL = (const float*)d_in[0];
    const float* fR = (const float*)d_in[1];
    const float* D  = (const float*)d_in[2];
    float* out  = (float*)d_out;
    float* ws   = (float*)d_ws;
    float* dref = ws;
    float* conf = ws + LOW;

    phase1<<<B_ * H4 * CHUNKS, 256, 0, stream>>>(fL, fR, D, dref, conf);
    phase2<<<(FULL / 4 + 255) / 256, 256, 0, stream>>>(dref, conf, out);
}